// Round 1
// baseline (11537.471 us; speedup 1.0000x reference)
//
#include <hip/hip_runtime.h>
#include <hip/hip_bf16.h>

// Sizes (fixed by the reference)
#define BN  256   // batch
#define SN  512   // seq len
#define INN 64    // input dim
#define HN  256   // hidden
#define MN  64    // motor

// LDS row strides (f16 elements). Pad so row stride mod 32 words == 4 (2-way banks)
#define ZINS 328  // zin: [x(64) | h(256)] + 8 pad
#define ZBS  264  // z0/z1 buffers: 256 + 8
#define CFS  72   // cfc buffer: 64 + 8

// Output offsets (f32 elements)
#define OFF_ACT  393216   // 256*512*3
#define OFF_CONF 524288   // + 256*512
#define OFF_HN   655360   // + 256*512

typedef _Float16 h8 __attribute__((ext_vector_type(8)));
typedef float fx4 __attribute__((ext_vector_type(4)));

__device__ __forceinline__ fx4 mfma16(h8 a, h8 b, fx4 c) {
    return __builtin_amdgcn_mfma_f32_16x16x32_f16(a, b, c, 0, 0, 0);
}

__device__ __forceinline__ float fast_tanh(float x) {
    // tanh(x) = 1 - 2/(e^{2x}+1); safe at +-inf
    float e = __expf(2.0f * x);
    return 1.0f - 2.0f / (e + 1.0f);
}
__device__ __forceinline__ float fast_sig(float x) {
    return 1.0f / (1.0f + __expf(-x));
}
__device__ __forceinline__ float lecun_tanh(float x) {
    return 1.7159f * fast_tanh(0.666f * x);
}
__device__ __forceinline__ float softplus_f(float x) {
    return fmaxf(x, 0.0f) + __logf(1.0f + __expf(-fabsf(x)));
}

// Load one MFMA B-fragment (K=32 slice, 16 cols) from a row-major f32 weight (K x N).
// lane l supplies B[kbase + j][col] for j=0..7 where kbase already includes (lane>>4)*8.
template <int NW>
__device__ __forceinline__ h8 loadB(const float* __restrict__ w, int col, int kbase) {
    h8 r;
#pragma unroll
    for (int j = 0; j < 8; ++j) r[j] = (_Float16)w[(kbase + j) * NW + col];
    return r;
}

__global__ __launch_bounds__(1024) void lh_scan_kernel(
    const float* __restrict__ x, const float* __restrict__ tsp, const float* __restrict__ hx,
    const float* __restrict__ w0, const float* __restrict__ b0,
    const float* __restrict__ w1, const float* __restrict__ b1,
    const float* __restrict__ f1w, const float* __restrict__ f1b,
    const float* __restrict__ f2w, const float* __restrict__ f2b,
    const float* __restrict__ taw, const float* __restrict__ tab,
    const float* __restrict__ tbw, const float* __restrict__ tbb,
    const float* __restrict__ pw, const float* __restrict__ pbias,
    const float* __restrict__ ihw0, const float* __restrict__ ihb0,
    const float* __restrict__ ihw1, const float* __restrict__ ihb1,
    const float* __restrict__ ahw0, const float* __restrict__ ahb0,
    const float* __restrict__ ahw1, const float* __restrict__ ahb1,
    const float* __restrict__ chw0, const float* __restrict__ chb0,
    const float* __restrict__ chw1, const float* __restrict__ chb1,
    float* __restrict__ out)
{
    __shared__ __align__(16) _Float16 zin[16 * ZINS];   // [x | h] per batch row
    __shared__ __align__(16) _Float16 zbA[16 * ZBS];    // backbone layer-0 output
    __shared__ __align__(16) _Float16 zbB[16 * ZBS];    // backbone layer-1 output
    __shared__ __align__(16) _Float16 cfcb[16 * CFS];   // proj output (lagged)
    __shared__ float hidI[16 * 16];
    __shared__ float hidA[16 * 16];
    __shared__ float hidC[16 * 8];
    __shared__ float tsb[2][16];
    __shared__ float wsm[80]; // [0..47] ihw1, [48..50] ihb1, [51..66] ahw1, [67] ahb1, [68..75] chw1, [76] chb1

    const int tid  = threadIdx.x;
    const int wv   = tid >> 6;
    const int lane = tid & 63;
    const int lo   = lane & 15;
    const int hi   = lane >> 4;
    const int hi8  = hi * 8;
    const int bg   = blockIdx.x * 16;      // first batch row of this group
    const int colw = wv * 16 + lo;         // this lane's output column (per 256-col matrix)

    // ---- small final-layer weights to LDS ----
    if (tid < 48)          wsm[tid] = ihw1[tid];
    else if (tid < 51)     wsm[tid] = ihb1[tid - 48];
    else if (tid < 67)     wsm[tid] = ahw1[tid - 51];
    else if (tid == 67)    wsm[67]  = ahb1[0];
    else if (tid < 76)     wsm[tid] = chw1[tid - 68];
    else if (tid == 76)    wsm[76]  = chb1[0];

    // ---- initial state: hx -> zin.h, x[:,0,:] -> zin.x, ts[:,0] ----
#pragma unroll
    for (int rep = 0; rep < 4; ++rep) {
        int idx = rep * 1024 + tid;        // 4096 = 16*256
        int r = idx >> 8, c = idx & 255;
        zin[r * ZINS + 64 + c] = (_Float16)hx[(bg + r) * HN + c];
    }
    {
        int r = tid >> 6, c = tid & 63;
        zin[r * ZINS + c] = (_Float16)x[((size_t)(bg + r) * SN + 0) * INN + c];
    }
    if (tid < 16) tsb[0][tid] = tsp[(bg + tid) * SN + 0];

    // ---- per-lane biases (one column per lane) ----
    const float b0v = b0[colw], b1v = b1[colw];
    const float v1b = f1b[colw], v2b = f2b[colw], vab = tab[colw], vbb = tbb[colw];

    // ---- register-resident weight fragments (live across all 512 steps) ----
    h8 w0f[10], w1f[8], q1f[8], q2f[8], qaf[8], qbf[8];
#pragma unroll
    for (int kk = 0; kk < 10; ++kk) w0f[kk] = loadB<256>(w0, colw, kk * 32 + hi8);
#pragma unroll
    for (int kk = 0; kk < 8; ++kk) {
        w1f[kk] = loadB<256>(w1,  colw, kk * 32 + hi8);
        q1f[kk] = loadB<256>(f1w, colw, kk * 32 + hi8);
        q2f[kk] = loadB<256>(f2w, colw, kk * 32 + hi8);
        qaf[kk] = loadB<256>(taw, colw, kk * 32 + hi8);
        qbf[kk] = loadB<256>(tbw, colw, kk * 32 + hi8);
    }
    h8 pf[8] = {};
    float pbv = 0.0f;
    if (wv < 4) {
        pbv = pbias[colw];
#pragma unroll
        for (int kk = 0; kk < 8; ++kk) pf[kk] = loadB<64>(pw, colw, kk * 32 + hi8);
    }
    h8 hwf[2] = {};
    float hbv = 0.0f;
    if (wv == 4) {
        hbv = ihb0[lo];
#pragma unroll
        for (int kk = 0; kk < 2; ++kk) hwf[kk] = loadB<16>(ihw0, lo, kk * 32 + hi8);
    } else if (wv == 5) {
        hbv = ahb0[lo];
#pragma unroll
        for (int kk = 0; kk < 2; ++kk) hwf[kk] = loadB<16>(ahw0, lo, kk * 32 + hi8);
    } else if (wv == 6) {
        int cc = (lo < 8) ? lo : 0;
        hbv = (lo < 8) ? chb0[lo] : 0.0f;
#pragma unroll
        for (int kk = 0; kk < 2; ++kk) hwf[kk] = loadB<8>(chw0, cc, kk * 32 + hi8);
    }

    __syncthreads();

    // ---- main scan: t = 0..S; t==S is the epilogue for the lagged cfc path ----
    for (int t = 0; t <= SN; ++t) {
        // ======== P1: z0 = lecun([x|h] @ W0 + b0); cfc(t-1) = h @ proj (waves 0-3) ========
        if (t < SN) {
            fx4 acc = {b0v, b0v, b0v, b0v};
#pragma unroll
            for (int kk = 0; kk < 10; ++kk) {
                h8 a = *(const h8*)&zin[lo * ZINS + kk * 32 + hi8];
                acc = mfma16(a, w0f[kk], acc);
            }
#pragma unroll
            for (int i = 0; i < 4; ++i)
                zbA[(hi * 4 + i) * ZBS + colw] = (_Float16)lecun_tanh(acc[i]);
        }
        if (t >= 1 && wv < 4) {
            fx4 acc = {pbv, pbv, pbv, pbv};
#pragma unroll
            for (int kk = 0; kk < 8; ++kk) {
                h8 a = *(const h8*)&zin[lo * ZINS + 64 + kk * 32 + hi8];
                acc = mfma16(a, pf[kk], acc);
            }
#pragma unroll
            for (int i = 0; i < 4; ++i)
                cfcb[(hi * 4 + i) * CFS + colw] = (_Float16)acc[i];
        }
        __syncthreads();

        // ======== P2: z1 = lecun(z0 @ W1 + b1); head hiddens (waves 4-6) ========
        if (t < SN) {
            fx4 acc = {b1v, b1v, b1v, b1v};
#pragma unroll
            for (int kk = 0; kk < 8; ++kk) {
                h8 a = *(const h8*)&zbA[lo * ZBS + kk * 32 + hi8];
                acc = mfma16(a, w1f[kk], acc);
            }
#pragma unroll
            for (int i = 0; i < 4; ++i)
                zbB[(hi * 4 + i) * ZBS + colw] = (_Float16)lecun_tanh(acc[i]);
        }
        if (t >= 1 && wv >= 4 && wv < 7) {
            fx4 acc = {hbv, hbv, hbv, hbv};
#pragma unroll
            for (int kk = 0; kk < 2; ++kk) {
                h8 a = *(const h8*)&cfcb[lo * CFS + kk * 32 + hi8];
                acc = mfma16(a, hwf[kk], acc);
            }
#pragma unroll
            for (int i = 0; i < 4; ++i) {
                float v = acc[i];
                v = v * fast_sig(v);  // silu
                int r = hi * 4 + i;
                if (wv == 4)       hidI[r * 16 + lo] = v;
                else if (wv == 5)  hidA[r * 16 + lo] = v;
                else if (lo < 8)   hidC[r * 8 + lo]  = v;
            }
        }
        __syncthreads();

        // ======== P3: four heads -> h_new; final tiny MLPs -> outputs(t-1); prefetch x/ts ========
        if (t < SN) {
            fx4 a1 = {v1b, v1b, v1b, v1b};
            fx4 a2 = {v2b, v2b, v2b, v2b};
            fx4 a3 = {vab, vab, vab, vab};
            fx4 a4 = {vbb, vbb, vbb, vbb};
#pragma unroll
            for (int kk = 0; kk < 8; ++kk) {
                h8 a = *(const h8*)&zbB[lo * ZBS + kk * 32 + hi8];
                a1 = mfma16(a, q1f[kk], a1);
                a2 = mfma16(a, q2f[kk], a2);
                a3 = mfma16(a, qaf[kk], a3);
                a4 = mfma16(a, qbf[kk], a4);
            }
#pragma unroll
            for (int i = 0; i < 4; ++i) {
                int r = hi * 4 + i;
                float tsv = tsb[t & 1][r];
                float ff1 = fast_tanh(a1[i]);
                float ff2 = fast_tanh(a2[i]);
                float ti  = fast_sig(a3[i] * tsv + a4[i]);
                float hn  = ff1 + ti * (ff2 - ff1);
                zin[r * ZINS + 64 + colw] = (_Float16)hn;
                if (t == SN - 1) out[OFF_HN + (bg + r) * HN + colw] = hn;
            }
            if (t + 1 < SN) {
                int r = tid >> 6, c = tid & 63;
                zin[r * ZINS + c] = (_Float16)x[((size_t)(bg + r) * SN + (t + 1)) * INN + c];
                if (tid < 16) tsb[(t + 1) & 1][tid] = tsp[(bg + tid) * SN + t + 1];
            }
        }
        if (t >= 1 && tid < 80) {
            int r = tid / 5, o = tid % 5;
            int tc = t - 1;
            int b = bg + r;
            if (o < 3) {
                float s = wsm[48 + o];
#pragma unroll
                for (int u = 0; u < 16; ++u) s += hidI[r * 16 + u] * wsm[u * 3 + o];
                out[(size_t)(b * SN + tc) * 3 + o] = softplus_f(s);
            } else if (o == 3) {
                float s = wsm[67];
#pragma unroll
                for (int u = 0; u < 16; ++u) s += hidA[r * 16 + u] * wsm[51 + u];
                out[OFF_ACT + b * SN + tc] = fast_tanh(s);
            } else {
                float s = wsm[76];
#pragma unroll
                for (int u = 0; u < 8; ++u) s += hidC[r * 8 + u] * wsm[68 + u];
                out[OFF_CONF + b * SN + tc] = fast_sig(s);
            }
        }
        __syncthreads();
    }
}

extern "C" void kernel_launch(void* const* d_in, const int* in_sizes, int n_in,
                              void* d_out, int out_size, void* d_ws, size_t ws_size,
                              hipStream_t stream) {
    (void)in_sizes; (void)n_in; (void)out_size; (void)d_ws; (void)ws_size;
    const float* p[29];
    for (int i = 0; i < 29; ++i) p[i] = (const float*)d_in[i];
    hipLaunchKernelGGL(lh_scan_kernel, dim3(16), dim3(1024), 0, stream,
        p[0], p[1], p[2], p[3], p[4], p[5], p[6], p[7], p[8], p[9], p[10], p[11], p[12],
        p[13], p[14], p[15], p[16], p[17], p[18], p[19], p[20], p[21], p[22], p[23],
        p[24], p[25], p[26], p[27], p[28], (float*)d_out);
}

// Round 2
// 6295.156 us; speedup vs baseline: 1.8328x; 1.8328x over previous
//
#include <hip/hip_runtime.h>
#include <hip/hip_bf16.h>

// Sizes (fixed by the reference)
#define BN  256
#define SN  512
#define INN 64
#define HN  256
#define MN  64

// LDS strides
#define ZINS 328   // zin: [x(64) | h(256)] + 8 pad (f16)
#define ZBS  264   // z0/z1: 256 + 8 (f16)
#define CFS  72    // cfc: 64 + 8 (f16)
#define HTS  33    // htmp row stride (f32)

// Output offsets (f32 elements)
#define OFF_ACT  393216
#define OFF_CONF 524288
#define OFF_HN   655360

typedef _Float16 h8 __attribute__((ext_vector_type(8)));
typedef float fx4 __attribute__((ext_vector_type(4)));

__device__ __forceinline__ fx4 mfma16(h8 a, h8 b, fx4 c) {
    return __builtin_amdgcn_mfma_f32_16x16x32_f16(a, b, c, 0, 0, 0);
}
__device__ __forceinline__ float fast_tanh(float x) {
    float e = __expf(2.0f * x);
    return 1.0f - 2.0f / (e + 1.0f);
}
__device__ __forceinline__ float fast_sig(float x) { return 1.0f / (1.0f + __expf(-x)); }
__device__ __forceinline__ float lecun_tanh(float x) { return 1.7159f * fast_tanh(0.666f * x); }
__device__ __forceinline__ float softplus_f(float x) {
    return fmaxf(x, 0.0f) + __logf(1.0f + __expf(-fabsf(x)));
}

template <int NW>
__device__ __forceinline__ h8 loadB(const float* __restrict__ w, int col, int kbase) {
    h8 r;
#pragma unroll
    for (int j = 0; j < 8; ++j) r[j] = (_Float16)w[(kbase + j) * NW + col];
    return r;
}

__global__ __launch_bounds__(512, 2) void lh_scan_kernel(
    const float* __restrict__ x, const float* __restrict__ tsp, const float* __restrict__ hx,
    const float* __restrict__ w0, const float* __restrict__ b0,
    const float* __restrict__ w1, const float* __restrict__ b1,
    const float* __restrict__ f1w, const float* __restrict__ f1b,
    const float* __restrict__ f2w, const float* __restrict__ f2b,
    const float* __restrict__ taw, const float* __restrict__ tab,
    const float* __restrict__ tbw, const float* __restrict__ tbb,
    const float* __restrict__ pw, const float* __restrict__ pbias,
    const float* __restrict__ ihw0, const float* __restrict__ ihb0,
    const float* __restrict__ ihw1, const float* __restrict__ ihb1,
    const float* __restrict__ ahw0, const float* __restrict__ ahb0,
    const float* __restrict__ ahw1, const float* __restrict__ ahb1,
    const float* __restrict__ chw0, const float* __restrict__ chb0,
    const float* __restrict__ chw1, const float* __restrict__ chb1,
    float* __restrict__ out, unsigned int* __restrict__ flags,
    _Float16* __restrict__ hbuf)
{
    __shared__ __align__(16) _Float16 zin[16 * ZINS];
    __shared__ __align__(16) _Float16 z0b[16 * ZBS];
    __shared__ __align__(16) _Float16 z1b[16 * ZBS];
    __shared__ __align__(16) _Float16 cfcb[16 * CFS];
    __shared__ __align__(16) float htmp[4 * 16 * HTS];
    __shared__ float hidI[16 * 16];
    __shared__ float hidA[16 * 16];
    __shared__ float hidC[16 * 8];
    __shared__ float tsb[2][16];
    __shared__ float wsm[80];

    const int tid  = threadIdx.x;
    const int wv   = tid >> 6;
    const int lane = tid & 63;
    const int lo   = lane & 15;
    const int hi   = lane >> 4;
    const int hi8  = hi * 8;

    const int bid   = blockIdx.x;
    const int xcd   = bid & 7;
    const int c     = (bid >> 3) & 7;     // column-slice id 0..7
    const int gsel  = bid >> 6;           // 0/1
    const int g     = xcd + 8 * gsel;     // batch group 0..15 (8 blocks share g, same XCD)
    const int bg    = g * 16;
    const int sbase = c * 32;             // this block's 32 head columns

    // ---- small final-layer weights to LDS ----
    if (tid < 48)          wsm[tid] = ihw1[tid];
    else if (tid < 51)     wsm[tid] = ihb1[tid - 48];
    else if (tid < 67)     wsm[tid] = ahw1[tid - 51];
    else if (tid == 67)    wsm[67]  = ahb1[0];
    else if (tid < 76)     wsm[tid] = chw1[tid - 68];
    else if (tid == 76)    wsm[76]  = chb1[0];

    // ---- initial state ----
    {
        int r = tid >> 5, c8 = (tid & 31) * 8;
#pragma unroll
        for (int j = 0; j < 8; ++j)
            zin[r * ZINS + 64 + c8 + j] = (_Float16)hx[(bg + r) * HN + c8 + j];
        int c2 = (tid & 31) * 2;
        const float* xp = &x[((size_t)(bg + r) * SN + 0) * INN + c2];
        zin[r * ZINS + c2]     = (_Float16)xp[0];
        zin[r * ZINS + c2 + 1] = (_Float16)xp[1];
    }
    if (tid < 16) tsb[0][tid] = tsp[(bg + tid) * SN + 0];

    // ---- per-lane column biases ----
    const int cg0 = wv, cg1 = wv + 8;         // z0/z1 column groups handled by this wave
    const float b00 = b0[cg0 * 16 + lo], b01 = b0[cg1 * 16 + lo];
    const float b10 = b1[cg0 * 16 + lo], b11 = b1[cg1 * 16 + lo];

    // head unit: matrix m = wv>>1 (f1,f2,ta,tb), local colgroup wv&1
    const int hm  = wv >> 1;
    const int hcol = sbase + (wv & 1) * 16 + lo;
    const float* hwp = (hm == 0) ? f1w : (hm == 1) ? f2w : (hm == 2) ? taw : tbw;
    const float* hbp = (hm == 0) ? f1b : (hm == 1) ? f2b : (hm == 2) ? tab : tbb;
    const float hb = hbp[hcol];

    // ---- register-resident weight fragments ----
    h8 w0f0[10], w0f1[10], w1f0[8], w1f1[8], hdf[8];
#pragma unroll
    for (int kk = 0; kk < 10; ++kk) {
        w0f0[kk] = loadB<256>(w0, cg0 * 16 + lo, kk * 32 + hi8);
        w0f1[kk] = loadB<256>(w0, cg1 * 16 + lo, kk * 32 + hi8);
    }
#pragma unroll
    for (int kk = 0; kk < 8; ++kk) {
        w1f0[kk] = loadB<256>(w1, cg0 * 16 + lo, kk * 32 + hi8);
        w1f1[kk] = loadB<256>(w1, cg1 * 16 + lo, kk * 32 + hi8);
        hdf[kk]  = loadB<256>(hwp, hcol, kk * 32 + hi8);
    }
    h8 pf[8] = {};
    float pbv = 0.0f;
    if (wv < 4) {
        pbv = pbias[wv * 16 + lo];
#pragma unroll
        for (int kk = 0; kk < 8; ++kk) pf[kk] = loadB<64>(pw, wv * 16 + lo, kk * 32 + hi8);
    }
    h8 hwf[2] = {};
    float hbv = 0.0f;
    if (wv == 4) {
        hbv = ihb0[lo];
#pragma unroll
        for (int kk = 0; kk < 2; ++kk) hwf[kk] = loadB<16>(ihw0, lo, kk * 32 + hi8);
    } else if (wv == 5) {
        hbv = ahb0[lo];
#pragma unroll
        for (int kk = 0; kk < 2; ++kk) hwf[kk] = loadB<16>(ahw0, lo, kk * 32 + hi8);
    } else if (wv == 6) {
        int cc = (lo < 8) ? lo : 0;
        hbv = (lo < 8) ? chb0[lo] : 0.0f;
#pragma unroll
        for (int kk = 0; kk < 2; ++kk) hwf[kk] = loadB<8>(chw0, cc, kk * 32 + hi8);
    }

    __syncthreads();

    for (int t = 0; t <= SN; ++t) {
        // ===== z0 = lecun([x|h] @ W0 + b0) =====
        if (t < SN) {
            fx4 a0 = {b00, b00, b00, b00}, a1 = {b01, b01, b01, b01};
#pragma unroll
            for (int kk = 0; kk < 10; ++kk) {
                h8 a = *(const h8*)&zin[lo * ZINS + kk * 32 + hi8];
                a0 = mfma16(a, w0f0[kk], a0);
                a1 = mfma16(a, w0f1[kk], a1);
            }
#pragma unroll
            for (int i = 0; i < 4; ++i) {
                int r = hi * 4 + i;
                z0b[r * ZBS + cg0 * 16 + lo] = (_Float16)lecun_tanh(a0[i]);
                z0b[r * ZBS + cg1 * 16 + lo] = (_Float16)lecun_tanh(a1[i]);
            }
        }
        __syncthreads();  // S1

        // ===== z1 = lecun(z0 @ W1 + b1) =====
        if (t < SN) {
            fx4 a0 = {b10, b10, b10, b10}, a1 = {b11, b11, b11, b11};
#pragma unroll
            for (int kk = 0; kk < 8; ++kk) {
                h8 a = *(const h8*)&z0b[lo * ZBS + kk * 32 + hi8];
                a0 = mfma16(a, w1f0[kk], a0);
                a1 = mfma16(a, w1f1[kk], a1);
            }
#pragma unroll
            for (int i = 0; i < 4; ++i) {
                int r = hi * 4 + i;
                z1b[r * ZBS + cg0 * 16 + lo] = (_Float16)lecun_tanh(a0[i]);
                z1b[r * ZBS + cg1 * 16 + lo] = (_Float16)lecun_tanh(a1[i]);
            }
        }
        __syncthreads();  // S2

        // ===== head unit: this wave's (matrix, colgroup) of the block's 32-col slice =====
        if (t < SN) {
            fx4 acc = {hb, hb, hb, hb};
#pragma unroll
            for (int kk = 0; kk < 8; ++kk) {
                h8 a = *(const h8*)&z1b[lo * ZBS + kk * 32 + hi8];
                acc = mfma16(a, hdf[kk], acc);
            }
#pragma unroll
            for (int i = 0; i < 4; ++i)
                htmp[(hm * 16 + hi * 4 + i) * HTS + (wv & 1) * 16 + lo] = acc[i];
        }
        __syncthreads();  // S3

        // ===== combine -> h_new slice -> global hbuf =====
        if (t < SN) {
            int r = tid >> 5, cc = tid & 31;
            float a1v = htmp[(0 * 16 + r) * HTS + cc];
            float a2v = htmp[(1 * 16 + r) * HTS + cc];
            float a3v = htmp[(2 * 16 + r) * HTS + cc];
            float a4v = htmp[(3 * 16 + r) * HTS + cc];
            float tv  = tsb[t & 1][r];
            float ff1 = fast_tanh(a1v);
            float ff2 = fast_tanh(a2v);
            float ti  = fast_sig(a3v * tv + a4v);
            float hn  = ff1 + ti * (ff2 - ff1);
            hbuf[((((size_t)((t + 1) & 1) * 16 + g) * 16) + r) * 256 + sbase + cc] = (_Float16)hn;
            if (t == SN - 1) out[OFF_HN + (bg + r) * HN + sbase + cc] = hn;
        }
        __syncthreads();  // S4 (drains stores: vmcnt(0) before barrier)
        if (t < SN && tid == 0)
            __hip_atomic_fetch_add(&flags[g], 1u, __ATOMIC_RELEASE, __HIP_MEMORY_SCOPE_AGENT);

        // ===== overlap phase (hides the inter-block barrier) =====
        // proj(t-1): waves 0-3 on block c==0
        if (t >= 1 && c == 0 && wv < 4) {
            fx4 acc = {pbv, pbv, pbv, pbv};
#pragma unroll
            for (int kk = 0; kk < 8; ++kk) {
                h8 a = *(const h8*)&zin[lo * ZINS + 64 + kk * 32 + hi8];
                acc = mfma16(a, pf[kk], acc);
            }
#pragma unroll
            for (int i = 0; i < 4; ++i)
                cfcb[(hi * 4 + i) * CFS + wv * 16 + lo] = (_Float16)acc[i];
        }
        // x/ts prefetch for t+1 (all blocks)
        if (t + 1 < SN) {
            int r = tid >> 5, c2 = (tid & 31) * 2;
            const float* xp = &x[((size_t)(bg + r) * SN + (t + 1)) * INN + c2];
            zin[r * ZINS + c2]     = (_Float16)xp[0];
            zin[r * ZINS + c2 + 1] = (_Float16)xp[1];
            if (tid < 16) tsb[(t + 1) & 1][tid] = tsp[(bg + tid) * SN + t + 1];
        }
        __syncthreads();  // S5

        if (t >= 1 && c == 0 && wv >= 4 && wv < 7) {
            fx4 acc = {hbv, hbv, hbv, hbv};
#pragma unroll
            for (int kk = 0; kk < 2; ++kk) {
                h8 a = *(const h8*)&cfcb[lo * CFS + kk * 32 + hi8];
                acc = mfma16(a, hwf[kk], acc);
            }
#pragma unroll
            for (int i = 0; i < 4; ++i) {
                float v = acc[i];
                v = v * fast_sig(v);
                int r = hi * 4 + i;
                if (wv == 4)       hidI[r * 16 + lo] = v;
                else if (wv == 5)  hidA[r * 16 + lo] = v;
                else if (lo < 8)   hidC[r * 8 + lo]  = v;
            }
        }
        __syncthreads();  // S6

        if (t >= 1 && c == 0 && tid < 80) {
            int r = tid / 5, o = tid % 5;
            int tc = t - 1;
            int b = bg + r;
            if (o < 3) {
                float s = wsm[48 + o];
#pragma unroll
                for (int u = 0; u < 16; ++u) s += hidI[r * 16 + u] * wsm[u * 3 + o];
                out[(size_t)(b * SN + tc) * 3 + o] = softplus_f(s);
            } else if (o == 3) {
                float s = wsm[67];
#pragma unroll
                for (int u = 0; u < 16; ++u) s += hidA[r * 16 + u] * wsm[51 + u];
                out[OFF_ACT + b * SN + tc] = fast_tanh(s);
            } else {
                float s = wsm[76];
#pragma unroll
                for (int u = 0; u < 8; ++u) s += hidC[r * 8 + u] * wsm[68 + u];
                out[OFF_CONF + b * SN + tc] = fast_sig(s);
            }
        }

        // ===== wait for all 8 blocks of the group, reload full h =====
        if (t < SN) {
            if (tid == 0) {
                unsigned target = 8u * (unsigned)(t + 1);
                while (__hip_atomic_load(&flags[g], __ATOMIC_ACQUIRE,
                                         __HIP_MEMORY_SCOPE_AGENT) < target) {}
            }
            __syncthreads();  // S7
            {
                int r = tid >> 5, c8 = (tid & 31) * 8;
                h8 hv = *(const h8*)&hbuf[((((size_t)((t + 1) & 1) * 16 + g) * 16) + r) * 256 + c8];
                *(h8*)&zin[r * ZINS + 64 + c8] = hv;
            }
        }
        __syncthreads();  // S8
    }
}

extern "C" void kernel_launch(void* const* d_in, const int* in_sizes, int n_in,
                              void* d_out, int out_size, void* d_ws, size_t ws_size,
                              hipStream_t stream) {
    (void)in_sizes; (void)n_in; (void)out_size; (void)ws_size;
    const float* p[29];
    for (int i = 0; i < 29; ++i) p[i] = (const float*)d_in[i];
    unsigned int* flags = (unsigned int*)d_ws;
    _Float16* hbuf = (_Float16*)((char*)d_ws + 256);
    hipMemsetAsync(d_ws, 0, 256, stream);
    hipLaunchKernelGGL(lh_scan_kernel, dim3(128), dim3(512), 0, stream,
        p[0], p[1], p[2], p[3], p[4], p[5], p[6], p[7], p[8], p[9], p[10], p[11], p[12],
        p[13], p[14], p[15], p[16], p[17], p[18], p[19], p[20], p[21], p[22], p[23],
        p[24], p[25], p[26], p[27], p[28], (float*)d_out, flags, hbuf);
}

// Round 3
// 4824.564 us; speedup vs baseline: 2.3914x; 1.3048x over previous
//
#include <hip/hip_runtime.h>
#include <hip/hip_bf16.h>

// Sizes (fixed by the reference)
#define BN  256
#define SN  512
#define INN 64
#define HN  256
#define MN  64

// LDS strides
#define ZINS 328   // zin: [x(64) | h(256)] + 8 pad (f16)
#define ZBS  264   // z0/z1: 256 + 8 (f16)
#define CFS  72    // cfc: 64 + 8 (f16)
#define HTS  33    // htmp row stride (f32)

// Output offsets (f32 elements)
#define OFF_ACT  393216
#define OFF_CONF 524288
#define OFF_HN   655360

typedef _Float16 h8 __attribute__((ext_vector_type(8)));
typedef float fx4 __attribute__((ext_vector_type(4)));

__device__ __forceinline__ fx4 mfma16(h8 a, h8 b, fx4 c) {
    return __builtin_amdgcn_mfma_f32_16x16x32_f16(a, b, c, 0, 0, 0);
}
__device__ __forceinline__ float fast_tanh(float x) {
    float e = __expf(2.0f * x);
    return 1.0f - 2.0f / (e + 1.0f);
}
__device__ __forceinline__ float fast_sig(float x) { return 1.0f / (1.0f + __expf(-x)); }
__device__ __forceinline__ float lecun_tanh(float x) { return 1.7159f * fast_tanh(0.666f * x); }
__device__ __forceinline__ float softplus_f(float x) {
    return fmaxf(x, 0.0f) + __logf(1.0f + __expf(-fabsf(x)));
}

template <int NW>
__device__ __forceinline__ h8 loadB(const float* __restrict__ w, int col, int kbase) {
    h8 r;
#pragma unroll
    for (int j = 0; j < 8; ++j) r[j] = (_Float16)w[(kbase + j) * NW + col];
    return r;
}

__global__ __attribute__((amdgpu_flat_work_group_size(512, 512), amdgpu_waves_per_eu(2, 2)))
void lh_scan_kernel(
    const float* __restrict__ x, const float* __restrict__ tsp, const float* __restrict__ hx,
    const float* __restrict__ w0, const float* __restrict__ b0,
    const float* __restrict__ w1, const float* __restrict__ b1,
    const float* __restrict__ f1w, const float* __restrict__ f1b,
    const float* __restrict__ f2w, const float* __restrict__ f2b,
    const float* __restrict__ taw, const float* __restrict__ tab,
    const float* __restrict__ tbw, const float* __restrict__ tbb,
    const float* __restrict__ pw, const float* __restrict__ pbias,
    const float* __restrict__ ihw0, const float* __restrict__ ihb0,
    const float* __restrict__ ihw1, const float* __restrict__ ihb1,
    const float* __restrict__ ahw0, const float* __restrict__ ahb0,
    const float* __restrict__ ahw1, const float* __restrict__ ahb1,
    const float* __restrict__ chw0, const float* __restrict__ chb0,
    const float* __restrict__ chw1, const float* __restrict__ chb1,
    float* __restrict__ out, unsigned int* __restrict__ flags,
    _Float16* __restrict__ hbuf)
{
    __shared__ __align__(16) _Float16 zin[16 * ZINS];
    __shared__ __align__(16) _Float16 z0b[16 * ZBS];
    __shared__ __align__(16) _Float16 z1b[16 * ZBS];
    __shared__ __align__(16) _Float16 cfcb[16 * CFS];
    __shared__ __align__(16) _Float16 pfl[8 * 4 * 64 * 8];  // proj B-frags: [kk][wv][lane][8]
    __shared__ __align__(16) float htmp[4 * 16 * HTS];
    __shared__ float hidI[16 * 16];
    __shared__ float hidA[16 * 16];
    __shared__ float hidC[16 * 8];
    __shared__ float tsb[2][16];
    __shared__ float wsm[80];

    const int tid  = threadIdx.x;
    const int wv   = tid >> 6;
    const int lane = tid & 63;
    const int lo   = lane & 15;
    const int hi   = lane >> 4;
    const int hi8  = hi * 8;

    const int bid   = blockIdx.x;
    const int xcd   = bid & 7;
    const int c     = (bid >> 3) & 7;     // column-slice id 0..7
    const int gsel  = bid >> 6;           // 0/1
    const int g     = xcd + 8 * gsel;     // batch group 0..15 (8 blocks share g, same XCD)
    const int bg    = g * 16;
    const int sbase = c * 32;             // this block's 32 head columns

    // ---- small final-layer weights to LDS ----
    if (tid < 48)          wsm[tid] = ihw1[tid];
    else if (tid < 51)     wsm[tid] = ihb1[tid - 48];
    else if (tid < 67)     wsm[tid] = ahw1[tid - 51];
    else if (tid == 67)    wsm[67]  = ahb1[0];
    else if (tid < 76)     wsm[tid] = chw1[tid - 68];
    else if (tid == 76)    wsm[76]  = chb1[0];

    // ---- initial state ----
    {
        int r = tid >> 5, c8 = (tid & 31) * 8;
#pragma unroll
        for (int j = 0; j < 8; ++j)
            zin[r * ZINS + 64 + c8 + j] = (_Float16)hx[(bg + r) * HN + c8 + j];
        int c2 = (tid & 31) * 2;
        const float* xp = &x[((size_t)(bg + r) * SN + 0) * INN + c2];
        zin[r * ZINS + c2]     = (_Float16)xp[0];
        zin[r * ZINS + c2 + 1] = (_Float16)xp[1];
    }
    if (tid < 16) tsb[0][tid] = tsp[(bg + tid) * SN + 0];

    // ---- per-lane column biases ----
    const int cg0 = wv, cg1 = wv + 8;
    const float b00 = b0[cg0 * 16 + lo], b01 = b0[cg1 * 16 + lo];
    const float b10 = b1[cg0 * 16 + lo], b11 = b1[cg1 * 16 + lo];

    const int hm  = wv >> 1;
    const int hcol = sbase + (wv & 1) * 16 + lo;
    const float* hwp = (hm == 0) ? f1w : (hm == 1) ? f2w : (hm == 2) ? taw : tbw;
    const float* hbp = (hm == 0) ? f1b : (hm == 1) ? f2b : (hm == 2) ? tab : tbb;
    const float hb = hbp[hcol];

    // ---- register-resident weight fragments ----
    h8 w0f0[10], w0f1[10], w1f0[8], w1f1[8], hdf[8];
#pragma unroll
    for (int kk = 0; kk < 10; ++kk) {
        w0f0[kk] = loadB<256>(w0, cg0 * 16 + lo, kk * 32 + hi8);
        w0f1[kk] = loadB<256>(w0, cg1 * 16 + lo, kk * 32 + hi8);
    }
#pragma unroll
    for (int kk = 0; kk < 8; ++kk) {
        w1f0[kk] = loadB<256>(w1, cg0 * 16 + lo, kk * 32 + hi8);
        w1f1[kk] = loadB<256>(w1, cg1 * 16 + lo, kk * 32 + hi8);
        hdf[kk]  = loadB<256>(hwp, hcol, kk * 32 + hi8);
    }
    // proj fragments -> LDS (block c==0 only; fragment-ordered so reads are b128)
    float pbv = 0.0f;
    if (c == 0 && wv < 4) {
        pbv = pbias[wv * 16 + lo];
#pragma unroll
        for (int kk = 0; kk < 8; ++kk) {
            h8 f = loadB<64>(pw, wv * 16 + lo, kk * 32 + hi8);
            *(h8*)&pfl[((kk * 4 + wv) * 64 + lane) * 8] = f;
        }
    }
    h8 hwf[2] = {};
    float hbv = 0.0f;
    if (wv == 4) {
        hbv = ihb0[lo];
#pragma unroll
        for (int kk = 0; kk < 2; ++kk) hwf[kk] = loadB<16>(ihw0, lo, kk * 32 + hi8);
    } else if (wv == 5) {
        hbv = ahb0[lo];
#pragma unroll
        for (int kk = 0; kk < 2; ++kk) hwf[kk] = loadB<16>(ahw0, lo, kk * 32 + hi8);
    } else if (wv == 6) {
        int cc = (lo < 8) ? lo : 0;
        hbv = (lo < 8) ? chb0[lo] : 0.0f;
#pragma unroll
        for (int kk = 0; kk < 2; ++kk) hwf[kk] = loadB<8>(chw0, cc, kk * 32 + hi8);
    }

    __syncthreads();

    for (int t = 0; t <= SN; ++t) {
        // ===== z0 = lecun([x|h] @ W0 + b0) =====
        if (t < SN) {
            fx4 a0 = {b00, b00, b00, b00}, a1 = {b01, b01, b01, b01};
#pragma unroll
            for (int kk = 0; kk < 10; ++kk) {
                h8 a = *(const h8*)&zin[lo * ZINS + kk * 32 + hi8];
                a0 = mfma16(a, w0f0[kk], a0);
                a1 = mfma16(a, w0f1[kk], a1);
            }
#pragma unroll
            for (int i = 0; i < 4; ++i) {
                int r = hi * 4 + i;
                z0b[r * ZBS + cg0 * 16 + lo] = (_Float16)lecun_tanh(a0[i]);
                z0b[r * ZBS + cg1 * 16 + lo] = (_Float16)lecun_tanh(a1[i]);
            }
        }
        __syncthreads();  // S1

        // ===== z1 = lecun(z0 @ W1 + b1) =====
        if (t < SN) {
            fx4 a0 = {b10, b10, b10, b10}, a1 = {b11, b11, b11, b11};
#pragma unroll
            for (int kk = 0; kk < 8; ++kk) {
                h8 a = *(const h8*)&z0b[lo * ZBS + kk * 32 + hi8];
                a0 = mfma16(a, w1f0[kk], a0);
                a1 = mfma16(a, w1f1[kk], a1);
            }
#pragma unroll
            for (int i = 0; i < 4; ++i) {
                int r = hi * 4 + i;
                z1b[r * ZBS + cg0 * 16 + lo] = (_Float16)lecun_tanh(a0[i]);
                z1b[r * ZBS + cg1 * 16 + lo] = (_Float16)lecun_tanh(a1[i]);
            }
        }
        __syncthreads();  // S2

        // ===== head unit: (matrix hm, colgroup wv&1) of this block's 32-col slice =====
        if (t < SN) {
            fx4 acc = {hb, hb, hb, hb};
#pragma unroll
            for (int kk = 0; kk < 8; ++kk) {
                h8 a = *(const h8*)&z1b[lo * ZBS + kk * 32 + hi8];
                acc = mfma16(a, hdf[kk], acc);
            }
#pragma unroll
            for (int i = 0; i < 4; ++i)
                htmp[(hm * 16 + hi * 4 + i) * HTS + (wv & 1) * 16 + lo] = acc[i];
        }
        __syncthreads();  // S3

        // ===== combine -> h_new slice -> global hbuf =====
        if (t < SN) {
            int r = tid >> 5, cc = tid & 31;
            float a1v = htmp[(0 * 16 + r) * HTS + cc];
            float a2v = htmp[(1 * 16 + r) * HTS + cc];
            float a3v = htmp[(2 * 16 + r) * HTS + cc];
            float a4v = htmp[(3 * 16 + r) * HTS + cc];
            float tv  = tsb[t & 1][r];
            float ff1 = fast_tanh(a1v);
            float ff2 = fast_tanh(a2v);
            float ti  = fast_sig(a3v * tv + a4v);
            float hn  = ff1 + ti * (ff2 - ff1);
            hbuf[((((size_t)((t + 1) & 1) * 16 + g) * 16) + r) * 256 + sbase + cc] = (_Float16)hn;
            if (t == SN - 1) out[OFF_HN + (bg + r) * HN + sbase + cc] = hn;
        }
        __syncthreads();  // S4
        if (t < SN && tid == 0)
            __hip_atomic_fetch_add(&flags[g], 1u, __ATOMIC_RELEASE, __HIP_MEMORY_SCOPE_AGENT);

        // ===== overlap phase (hides the inter-block barrier) =====
        if (t >= 1 && c == 0 && wv < 4) {
            fx4 acc = {pbv, pbv, pbv, pbv};
#pragma unroll
            for (int kk = 0; kk < 8; ++kk) {
                h8 a = *(const h8*)&zin[lo * ZINS + 64 + kk * 32 + hi8];
                h8 b = *(const h8*)&pfl[((kk * 4 + wv) * 64 + lane) * 8];
                acc = mfma16(a, b, acc);
            }
#pragma unroll
            for (int i = 0; i < 4; ++i)
                cfcb[(hi * 4 + i) * CFS + wv * 16 + lo] = (_Float16)acc[i];
        }
        if (t + 1 < SN) {
            int r = tid >> 5, c2 = (tid & 31) * 2;
            const float* xp = &x[((size_t)(bg + r) * SN + (t + 1)) * INN + c2];
            zin[r * ZINS + c2]     = (_Float16)xp[0];
            zin[r * ZINS + c2 + 1] = (_Float16)xp[1];
            if (tid < 16) tsb[(t + 1) & 1][tid] = tsp[(bg + tid) * SN + t + 1];
        }
        __syncthreads();  // S5

        if (t >= 1 && c == 0 && wv >= 4 && wv < 7) {
            fx4 acc = {hbv, hbv, hbv, hbv};
#pragma unroll
            for (int kk = 0; kk < 2; ++kk) {
                h8 a = *(const h8*)&cfcb[lo * CFS + kk * 32 + hi8];
                acc = mfma16(a, hwf[kk], acc);
            }
#pragma unroll
            for (int i = 0; i < 4; ++i) {
                float v = acc[i];
                v = v * fast_sig(v);
                int r = hi * 4 + i;
                if (wv == 4)       hidI[r * 16 + lo] = v;
                else if (wv == 5)  hidA[r * 16 + lo] = v;
                else if (lo < 8)   hidC[r * 8 + lo]  = v;
            }
        }
        __syncthreads();  // S6

        if (t >= 1 && c == 0 && tid < 80) {
            int r = tid / 5, o = tid % 5;
            int tc = t - 1;
            int b = bg + r;
            if (o < 3) {
                float s = wsm[48 + o];
#pragma unroll
                for (int u = 0; u < 16; ++u) s += hidI[r * 16 + u] * wsm[u * 3 + o];
                out[(size_t)(b * SN + tc) * 3 + o] = softplus_f(s);
            } else if (o == 3) {
                float s = wsm[67];
#pragma unroll
                for (int u = 0; u < 16; ++u) s += hidA[r * 16 + u] * wsm[51 + u];
                out[OFF_ACT + b * SN + tc] = fast_tanh(s);
            } else {
                float s = wsm[76];
#pragma unroll
                for (int u = 0; u < 8; ++u) s += hidC[r * 8 + u] * wsm[68 + u];
                out[OFF_CONF + b * SN + tc] = fast_sig(s);
            }
        }

        // ===== wait for all 8 blocks of the group, reload full h =====
        if (t < SN) {
            if (tid == 0) {
                unsigned target = 8u * (unsigned)(t + 1);
                while (__hip_atomic_load(&flags[g], __ATOMIC_ACQUIRE,
                                         __HIP_MEMORY_SCOPE_AGENT) < target) {}
            }
            __syncthreads();  // S7
            {
                int r = tid >> 5, c8 = (tid & 31) * 8;
                h8 hv = *(const h8*)&hbuf[((((size_t)((t + 1) & 1) * 16 + g) * 16) + r) * 256 + c8];
                *(h8*)&zin[r * ZINS + 64 + c8] = hv;
            }
        }
        __syncthreads();  // S8
    }
}

extern "C" void kernel_launch(void* const* d_in, const int* in_sizes, int n_in,
                              void* d_out, int out_size, void* d_ws, size_t ws_size,
                              hipStream_t stream) {
    (void)in_sizes; (void)n_in; (void)out_size; (void)ws_size;
    const float* p[29];
    for (int i = 0; i < 29; ++i) p[i] = (const float*)d_in[i];
    unsigned int* flags = (unsigned int*)d_ws;
    _Float16* hbuf = (_Float16*)((char*)d_ws + 256);
    hipMemsetAsync(d_ws, 0, 256, stream);
    hipLaunchKernelGGL(lh_scan_kernel, dim3(128), dim3(512), 0, stream,
        p[0], p[1], p[2], p[3], p[4], p[5], p[6], p[7], p[8], p[9], p[10], p[11], p[12],
        p[13], p[14], p[15], p[16], p[17], p[18], p[19], p[20], p[21], p[22], p[23],
        p[24], p[25], p[26], p[27], p[28], (float*)d_out, flags, hbuf);
}

// Round 4
// 3040.668 us; speedup vs baseline: 3.7944x; 1.5867x over previous
//
#include <hip/hip_runtime.h>
#include <hip/hip_bf16.h>

// Sizes (fixed by the reference)
#define BN  256
#define SN  512
#define INN 64
#define HN  256
#define MN  64

// LDS strides
#define ZINS 328   // zin: [x(64) | h(256)] + 8 pad (f16)
#define ZBS  264   // z0/z1: 256 + 8 (f16)
#define CFS  72    // cfc: 64 + 8 (f16)
#define HTS  33    // htmp row stride (f32)

// Output offsets (f32 elements)
#define OFF_ACT  393216
#define OFF_CONF 524288
#define OFF_HN   655360

typedef _Float16 h8 __attribute__((ext_vector_type(8)));
typedef float fx4 __attribute__((ext_vector_type(4)));

__device__ __forceinline__ fx4 mfma16(h8 a, h8 b, fx4 c) {
    return __builtin_amdgcn_mfma_f32_16x16x32_f16(a, b, c, 0, 0, 0);
}
__device__ __forceinline__ float fast_tanh(float x) {
    float e = __expf(2.0f * x);
    return 1.0f - 2.0f / (e + 1.0f);
}
__device__ __forceinline__ float fast_sig(float x) { return 1.0f / (1.0f + __expf(-x)); }
__device__ __forceinline__ float lecun_tanh(float x) { return 1.7159f * fast_tanh(0.666f * x); }
__device__ __forceinline__ float softplus_f(float x) {
    return fmaxf(x, 0.0f) + __logf(1.0f + __expf(-fabsf(x)));
}

template <int NW>
__device__ __forceinline__ h8 loadB(const float* __restrict__ w, int col, int kbase) {
    h8 r;
#pragma unroll
    for (int j = 0; j < 8; ++j) r[j] = (_Float16)w[(kbase + j) * NW + col];
    return r;
}

__global__ void __launch_bounds__(512, 1) lh_scan_kernel(
    const float* __restrict__ x, const float* __restrict__ tsp, const float* __restrict__ hx,
    const float* __restrict__ w0, const float* __restrict__ b0,
    const float* __restrict__ w1, const float* __restrict__ b1,
    const float* __restrict__ f1w, const float* __restrict__ f1b,
    const float* __restrict__ f2w, const float* __restrict__ f2b,
    const float* __restrict__ taw, const float* __restrict__ tab,
    const float* __restrict__ tbw, const float* __restrict__ tbb,
    const float* __restrict__ pw, const float* __restrict__ pbias,
    const float* __restrict__ ihw0, const float* __restrict__ ihb0,
    const float* __restrict__ ihw1, const float* __restrict__ ihb1,
    const float* __restrict__ ahw0, const float* __restrict__ ahb0,
    const float* __restrict__ ahw1, const float* __restrict__ ahb1,
    const float* __restrict__ chw0, const float* __restrict__ chb0,
    const float* __restrict__ chw1, const float* __restrict__ chb1,
    float* __restrict__ out, unsigned int* __restrict__ flags,
    _Float16* __restrict__ hbuf)
{
    __shared__ __align__(16) _Float16 zin[16 * ZINS];
    __shared__ __align__(16) _Float16 z0b[16 * ZBS];
    __shared__ __align__(16) _Float16 z1b[16 * ZBS];
    __shared__ __align__(16) _Float16 cfcb[16 * CFS];
    __shared__ __align__(16) _Float16 pfl[8 * 4 * 64 * 8];   // proj B-frags: [kk][wv][lane][8]
    __shared__ __align__(16) _Float16 w1l[8 * 8 * 64 * 8];   // W1 cg1 B-frags: [kk][wv][lane][8]
    __shared__ __align__(16) float htmp[4 * 16 * HTS];
    __shared__ float hidI[16 * 16];
    __shared__ float hidA[16 * 16];
    __shared__ float hidC[16 * 8];
    __shared__ float tsb[2][16];
    __shared__ float wsm[80];

    const int tid  = threadIdx.x;
    const int wv   = tid >> 6;
    const int lane = tid & 63;
    const int lo   = lane & 15;
    const int hi   = lane >> 4;
    const int hi8  = hi * 8;

    const int bid   = blockIdx.x;
    const int xcd   = bid & 7;
    const int c     = (bid >> 3) & 7;     // column-slice id 0..7
    const int gsel  = bid >> 6;           // 0/1
    const int g     = xcd + 8 * gsel;     // batch group 0..15 (8 blocks share g, same XCD)
    const int bg    = g * 16;
    const int sbase = c * 32;             // this block's 32 head columns

    // ---- small final-layer weights to LDS ----
    if (tid < 48)          wsm[tid] = ihw1[tid];
    else if (tid < 51)     wsm[tid] = ihb1[tid - 48];
    else if (tid < 67)     wsm[tid] = ahw1[tid - 51];
    else if (tid == 67)    wsm[67]  = ahb1[0];
    else if (tid < 76)     wsm[tid] = chw1[tid - 68];
    else if (tid == 76)    wsm[76]  = chb1[0];

    // ---- initial state ----
    {
        int r = tid >> 5, c8 = (tid & 31) * 8;
#pragma unroll
        for (int j = 0; j < 8; ++j)
            zin[r * ZINS + 64 + c8 + j] = (_Float16)hx[(bg + r) * HN + c8 + j];
        int c2 = (tid & 31) * 2;
        const float* xp = &x[((size_t)(bg + r) * SN + 0) * INN + c2];
        zin[r * ZINS + c2]     = (_Float16)xp[0];
        zin[r * ZINS + c2 + 1] = (_Float16)xp[1];
    }
    if (tid < 16) tsb[0][tid] = tsp[(bg + tid) * SN + 0];

    // ---- per-lane column biases ----
    const int cg0 = wv, cg1 = wv + 8;
    const float b00 = b0[cg0 * 16 + lo], b01 = b0[cg1 * 16 + lo];
    const float b10 = b1[cg0 * 16 + lo], b11 = b1[cg1 * 16 + lo];

    const int hm  = wv >> 1;
    const int hcol = sbase + (wv & 1) * 16 + lo;
    const float* hwp = (hm == 0) ? f1w : (hm == 1) ? f2w : (hm == 2) ? taw : tbw;
    const float* hbp = (hm == 0) ? f1b : (hm == 1) ? f2b : (hm == 2) ? tab : tbb;
    const float hb = hbp[hcol];

    // ---- register-resident weight fragments (W0 both cgs, W1 cg0, head unit) ----
    h8 w0f0[10], w0f1[10], w1f0[8], hdf[8];
#pragma unroll
    for (int kk = 0; kk < 10; ++kk) {
        w0f0[kk] = loadB<256>(w0, cg0 * 16 + lo, kk * 32 + hi8);
        w0f1[kk] = loadB<256>(w0, cg1 * 16 + lo, kk * 32 + hi8);
    }
#pragma unroll
    for (int kk = 0; kk < 8; ++kk) {
        w1f0[kk] = loadB<256>(w1, cg0 * 16 + lo, kk * 32 + hi8);
        hdf[kk]  = loadB<256>(hwp, hcol, kk * 32 + hi8);
        // W1 cg1 fragments -> LDS (all blocks)
        h8 f = loadB<256>(w1, cg1 * 16 + lo, kk * 32 + hi8);
        *(h8*)&w1l[((kk * 8 + wv) * 64 + lane) * 8] = f;
    }
    // proj fragments -> LDS (block c==0 only)
    float pbv = 0.0f;
    if (c == 0 && wv < 4) {
        pbv = pbias[wv * 16 + lo];
#pragma unroll
        for (int kk = 0; kk < 8; ++kk) {
            h8 f = loadB<64>(pw, wv * 16 + lo, kk * 32 + hi8);
            *(h8*)&pfl[((kk * 4 + wv) * 64 + lane) * 8] = f;
        }
    }
    h8 hwf[2] = {};
    float hbv = 0.0f;
    if (wv == 4) {
        hbv = ihb0[lo];
#pragma unroll
        for (int kk = 0; kk < 2; ++kk) hwf[kk] = loadB<16>(ihw0, lo, kk * 32 + hi8);
    } else if (wv == 5) {
        hbv = ahb0[lo];
#pragma unroll
        for (int kk = 0; kk < 2; ++kk) hwf[kk] = loadB<16>(ahw0, lo, kk * 32 + hi8);
    } else if (wv == 6) {
        int cc = (lo < 8) ? lo : 0;
        hbv = (lo < 8) ? chb0[lo] : 0.0f;
#pragma unroll
        for (int kk = 0; kk < 2; ++kk) hwf[kk] = loadB<8>(chw0, cc, kk * 32 + hi8);
    }

    __syncthreads();

    for (int t = 0; t <= SN; ++t) {
        // ===== z0 = lecun([x|h] @ W0 + b0) =====
        if (t < SN) {
            fx4 a0 = {b00, b00, b00, b00}, a1 = {b01, b01, b01, b01};
#pragma unroll
            for (int kk = 0; kk < 10; ++kk) {
                h8 a = *(const h8*)&zin[lo * ZINS + kk * 32 + hi8];
                a0 = mfma16(a, w0f0[kk], a0);
                a1 = mfma16(a, w0f1[kk], a1);
            }
#pragma unroll
            for (int i = 0; i < 4; ++i) {
                int r = hi * 4 + i;
                z0b[r * ZBS + cg0 * 16 + lo] = (_Float16)lecun_tanh(a0[i]);
                z0b[r * ZBS + cg1 * 16 + lo] = (_Float16)lecun_tanh(a1[i]);
            }
        }
        __syncthreads();  // S1

        // ===== z1 = lecun(z0 @ W1 + b1) =====
        if (t < SN) {
            fx4 a0 = {b10, b10, b10, b10}, a1 = {b11, b11, b11, b11};
#pragma unroll
            for (int kk = 0; kk < 8; ++kk) {
                h8 a = *(const h8*)&z0b[lo * ZBS + kk * 32 + hi8];
                h8 b1f = *(const h8*)&w1l[((kk * 8 + wv) * 64 + lane) * 8];
                a0 = mfma16(a, w1f0[kk], a0);
                a1 = mfma16(a, b1f, a1);
            }
#pragma unroll
            for (int i = 0; i < 4; ++i) {
                int r = hi * 4 + i;
                z1b[r * ZBS + cg0 * 16 + lo] = (_Float16)lecun_tanh(a0[i]);
                z1b[r * ZBS + cg1 * 16 + lo] = (_Float16)lecun_tanh(a1[i]);
            }
        }
        __syncthreads();  // S2

        // ===== head unit: (matrix hm, colgroup wv&1) of this block's 32-col slice =====
        if (t < SN) {
            fx4 acc = {hb, hb, hb, hb};
#pragma unroll
            for (int kk = 0; kk < 8; ++kk) {
                h8 a = *(const h8*)&z1b[lo * ZBS + kk * 32 + hi8];
                acc = mfma16(a, hdf[kk], acc);
            }
#pragma unroll
            for (int i = 0; i < 4; ++i)
                htmp[(hm * 16 + hi * 4 + i) * HTS + (wv & 1) * 16 + lo] = acc[i];
        }
        __syncthreads();  // S3

        // ===== combine -> h_new slice -> global hbuf =====
        if (t < SN) {
            int r = tid >> 5, cc = tid & 31;
            float a1v = htmp[(0 * 16 + r) * HTS + cc];
            float a2v = htmp[(1 * 16 + r) * HTS + cc];
            float a3v = htmp[(2 * 16 + r) * HTS + cc];
            float a4v = htmp[(3 * 16 + r) * HTS + cc];
            float tv  = tsb[t & 1][r];
            float ff1 = fast_tanh(a1v);
            float ff2 = fast_tanh(a2v);
            float ti  = fast_sig(a3v * tv + a4v);
            float hn  = ff1 + ti * (ff2 - ff1);
            hbuf[((((size_t)((t + 1) & 1) * 16 + g) * 16) + r) * 256 + sbase + cc] = (_Float16)hn;
            if (t == SN - 1) out[OFF_HN + (bg + r) * HN + sbase + cc] = hn;
        }
        __syncthreads();  // S4
        if (t < SN && tid == 0)
            __hip_atomic_fetch_add(&flags[g], 1u, __ATOMIC_RELEASE, __HIP_MEMORY_SCOPE_AGENT);

        // ===== overlap phase (hides the inter-block barrier) =====
        if (t >= 1 && c == 0 && wv < 4) {
            fx4 acc = {pbv, pbv, pbv, pbv};
#pragma unroll
            for (int kk = 0; kk < 8; ++kk) {
                h8 a = *(const h8*)&zin[lo * ZINS + 64 + kk * 32 + hi8];
                h8 b = *(const h8*)&pfl[((kk * 4 + wv) * 64 + lane) * 8];
                acc = mfma16(a, b, acc);
            }
#pragma unroll
            for (int i = 0; i < 4; ++i)
                cfcb[(hi * 4 + i) * CFS + wv * 16 + lo] = (_Float16)acc[i];
        }
        if (t + 1 < SN) {
            int r = tid >> 5, c2 = (tid & 31) * 2;
            const float* xp = &x[((size_t)(bg + r) * SN + (t + 1)) * INN + c2];
            zin[r * ZINS + c2]     = (_Float16)xp[0];
            zin[r * ZINS + c2 + 1] = (_Float16)xp[1];
            if (tid < 16) tsb[(t + 1) & 1][tid] = tsp[(bg + tid) * SN + t + 1];
        }
        __syncthreads();  // S5

        if (t >= 1 && c == 0 && wv >= 4 && wv < 7) {
            fx4 acc = {hbv, hbv, hbv, hbv};
#pragma unroll
            for (int kk = 0; kk < 2; ++kk) {
                h8 a = *(const h8*)&cfcb[lo * CFS + kk * 32 + hi8];
                acc = mfma16(a, hwf[kk], acc);
            }
#pragma unroll
            for (int i = 0; i < 4; ++i) {
                float v = acc[i];
                v = v * fast_sig(v);
                int r = hi * 4 + i;
                if (wv == 4)       hidI[r * 16 + lo] = v;
                else if (wv == 5)  hidA[r * 16 + lo] = v;
                else if (lo < 8)   hidC[r * 8 + lo]  = v;
            }
        }
        __syncthreads();  // S6

        if (t >= 1 && c == 0 && tid < 80) {
            int r = tid / 5, o = tid % 5;
            int tc = t - 1;
            int b = bg + r;
            if (o < 3) {
                float s = wsm[48 + o];
#pragma unroll
                for (int u = 0; u < 16; ++u) s += hidI[r * 16 + u] * wsm[u * 3 + o];
                out[(size_t)(b * SN + tc) * 3 + o] = softplus_f(s);
            } else if (o == 3) {
                float s = wsm[67];
#pragma unroll
                for (int u = 0; u < 16; ++u) s += hidA[r * 16 + u] * wsm[51 + u];
                out[OFF_ACT + b * SN + tc] = fast_tanh(s);
            } else {
                float s = wsm[76];
#pragma unroll
                for (int u = 0; u < 8; ++u) s += hidC[r * 8 + u] * wsm[68 + u];
                out[OFF_CONF + b * SN + tc] = fast_sig(s);
            }
        }

        // ===== wait for all 8 blocks of the group, reload full h =====
        if (t < SN) {
            if (tid == 0) {
                unsigned target = 8u * (unsigned)(t + 1);
                while (__hip_atomic_load(&flags[g], __ATOMIC_ACQUIRE,
                                         __HIP_MEMORY_SCOPE_AGENT) < target) {}
            }
            __syncthreads();  // S7
            {
                int r = tid >> 5, c8 = (tid & 31) * 8;
                h8 hv = *(const h8*)&hbuf[((((size_t)((t + 1) & 1) * 16 + g) * 16) + r) * 256 + c8];
                *(h8*)&zin[r * ZINS + 64 + c8] = hv;
            }
        }
        __syncthreads();  // S8
    }
}

extern "C" void kernel_launch(void* const* d_in, const int* in_sizes, int n_in,
                              void* d_out, int out_size, void* d_ws, size_t ws_size,
                              hipStream_t stream) {
    (void)in_sizes; (void)n_in; (void)out_size; (void)ws_size;
    const float* p[29];
    for (int i = 0; i < 29; ++i) p[i] = (const float*)d_in[i];
    unsigned int* flags = (unsigned int*)d_ws;
    _Float16* hbuf = (_Float16*)((char*)d_ws + 256);
    hipMemsetAsync(d_ws, 0, 256, stream);
    hipLaunchKernelGGL(lh_scan_kernel, dim3(128), dim3(512), 0, stream,
        p[0], p[1], p[2], p[3], p[4], p[5], p[6], p[7], p[8], p[9], p[10], p[11], p[12],
        p[13], p[14], p[15], p[16], p[17], p[18], p[19], p[20], p[21], p[22], p[23],
        p[24], p[25], p[26], p[27], p[28], (float*)d_out, flags, hbuf);
}